// Round 10
// baseline (206.581 us; speedup 1.0000x reference)
//
#include <hip/hip_runtime.h>
#include <math.h>
#include <float.h>

#define DDIM 1024   // D
#define PDIM 32     // pattern_dim
#define NPAT 256    // n_patterns
#define TOPK 4
#define BLOCK 256
#define GT   16     // tokens per tile
#define DCHP 128    // d-chunk
#define NCHP 8      // d-chunks (DDIM/DCHP)
#define RTPB 4      // tokens per route block (one per wave)

// ---------------------------------------------------------------------------
// K0 (R16): routing, one WAVE per token, 4 tokens/block, 512 blocks.
// De-staged hasher: hasher_w is a single shared 128 KB block, fully
// L2-resident and broadcast to all waves -> read directly (Common-mistake #7:
// don't LDS-stage data that L2-fits). This is the R0-baseline hash loop
// (verbatim-validated); removes 8 barriers + staging stream per block.
// Top4/softmax/gcount logic verbatim from R9 (validated at 183 us).
__global__ __launch_bounds__(BLOCK) void route_kernel(
    const float* __restrict__ x,
    const float* __restrict__ hasher_w,   // [PDIM, DDIM]
    const float* __restrict__ keys,       // [NPAT, PDIM]
    int*   __restrict__ tki,              // [ntok, TOPK]
    float* __restrict__ tkw,              // [ntok, TOPK]
    int*   __restrict__ gcount,           // [NPAT], pre-zeroed
    int ntok)
{
    __shared__ float P_s[RTPB][64 * 33];  // 33.8 KB transpose scratch
    __shared__ float h_s[RTPB][32];

    const int tid  = threadIdx.x;
    const int wv   = tid >> 6;
    const int lane = tid & 63;
    const int traw = blockIdx.x * RTPB + wv;
    const int tok  = min(traw, ntok - 1);

    // ---- x row into registers (coalesced float4)
    const float4* xrow = (const float4*)(x + (size_t)tok * DDIM);
    float4 xr[4];
    #pragma unroll
    for (int i = 0; i < 4; ++i) xr[i] = xrow[i * 64 + lane];

    // ---- per-lane partial h[pp]: hasher read DIRECTLY from global (L2 bcast)
    float part[PDIM];
    #pragma unroll
    for (int pp = 0; pp < PDIM; ++pp) {
        const float4* wrow = (const float4*)(hasher_w + (size_t)pp * DDIM);
        float a = 0.f;
        #pragma unroll
        for (int i = 0; i < 4; ++i) {
            const float4 w4 = wrow[i * 64 + lane];
            a = fmaf(xr[i].x, w4.x, a); a = fmaf(xr[i].y, w4.y, a);
            a = fmaf(xr[i].z, w4.z, a); a = fmaf(xr[i].w, w4.w, a);
        }
        part[pp] = a;
    }

    // ---- transpose-reduce: P[l][pp] -> h[pp]
    float* P = P_s[wv];
    #pragma unroll
    for (int pp = 0; pp < PDIM; ++pp) P[lane * 33 + pp] = part[pp];
    __syncthreads();

    {
        const int pp = lane & 31, half = lane >> 5;
        float hsum = 0.f;
        #pragma unroll 8
        for (int i = 0; i < 32; ++i)
            hsum += P[(half * 32 + i) * 33 + pp];
        hsum += __shfl_xor(hsum, 32, 64);
        if (half == 0) h_s[wv][pp] = hsum;
    }
    __syncthreads();

    // ---- sim + top4 + softmax (verbatim logic, validated)
    float4 h4[8];
    #pragma unroll
    for (int i = 0; i < 8; ++i) h4[i] = *(const float4*)&h_s[wv][i * 4];

    float sc0, sc1, sc2, sc3;
    {
        float sv[4];
        #pragma unroll
        for (int c = 0; c < 4; ++c) {
            const float4* kr = (const float4*)(keys + (size_t)(c * 64 + lane) * PDIM);
            float a = 0.f;
            #pragma unroll
            for (int i = 0; i < 8; ++i) {
                const float4 k4 = kr[i];
                a = fmaf(k4.x, h4[i].x, a); a = fmaf(k4.y, h4[i].y, a);
                a = fmaf(k4.z, h4[i].z, a); a = fmaf(k4.w, h4[i].w, a);
            }
            sv[c] = a;
        }
        sc0 = sv[0]; sc1 = sv[1]; sc2 = sv[2]; sc3 = sv[3];
    }

    float wval[TOPK]; int widx[TOPK];
    #pragma unroll
    for (int r = 0; r < TOPK; ++r) {
        float bv = sc0; int bc = 0;
        if (sc1 > bv) { bv = sc1; bc = 1; }
        if (sc2 > bv) { bv = sc2; bc = 2; }
        if (sc3 > bv) { bv = sc3; bc = 3; }
        int bidx = bc * 64 + lane;
        #pragma unroll
        for (int off = 1; off < 64; off <<= 1) {
            const float ov = __shfl_xor(bv, off, 64);
            const int   oi = __shfl_xor(bidx, off, 64);
            if (ov > bv || (ov == bv && oi < bidx)) { bv = ov; bidx = oi; }
        }
        wval[r] = bv; widx[r] = bidx;
        if ((bidx & 63) == lane) {
            const int c = bidx >> 6;
            if (c == 0) sc0 = -FLT_MAX;
            else if (c == 1) sc1 = -FLT_MAX;
            else if (c == 2) sc2 = -FLT_MAX;
            else sc3 = -FLT_MAX;
        }
    }

    if (lane == 0 && traw < ntok) {
        float m = wval[0];
        #pragma unroll
        for (int k = 1; k < TOPK; ++k) m = fmaxf(m, wval[k]);
        float s = 0.f, e[TOPK];
        #pragma unroll
        for (int k = 0; k < TOPK; ++k) { e[k] = expf(wval[k] - m); s += e[k]; }
        #pragma unroll
        for (int k = 0; k < TOPK; ++k) {
            tki[tok * TOPK + k] = widx[k];
            tkw[tok * TOPK + k] = e[k] / s;
            atomicAdd(&gcount[widx[k]], 1);
        }
    }
}

// ---------------------------------------------------------------------------
// K1a (R12, validated): scan gcount -> offs, init gcur, tile list.
__global__ __launch_bounds__(NPAT) void scan_kernel(
    const int* __restrict__ gcount,
    int* __restrict__ offs,
    int* __restrict__ gcur,
    int* __restrict__ tile2p, int* __restrict__ tilei,
    int maxt)
{
    __shared__ int s[NPAT];
    const int tid = threadIdx.x;

    const int v = gcount[tid];
    s[tid] = v;
    __syncthreads();
    for (int off = 1; off < NPAT; off <<= 1) {
        int t = 0;
        if (tid >= off) t = s[tid - off];
        __syncthreads();
        s[tid] += t;
        __syncthreads();
    }
    const int incl = s[tid];
    offs[tid + 1] = incl;
    if (tid == 0) offs[0] = 0;
    gcur[tid] = incl - v;

    const int tc = (v + GT - 1) / GT;
    __syncthreads();
    s[tid] = tc;
    __syncthreads();
    for (int off = 1; off < NPAT; off <<= 1) {
        int t = 0;
        if (tid >= off) t = s[tid - off];
        __syncthreads();
        s[tid] += t;
        __syncthreads();
    }
    const int toff = s[tid] - tc;
    for (int i = tid; i < maxt; i += NPAT) tile2p[i] = -1;
    __syncthreads();
    for (int i = 0; i < tc; ++i) { tile2p[toff + i] = tid; tilei[toff + i] = i; }
}

// ---------------------------------------------------------------------------
// K1b (R12, validated): parallel CSR fill.
__global__ __launch_bounds__(BLOCK) void fill_kernel(
    const int* __restrict__ tki, const float* __restrict__ tkw,
    const float* __restrict__ scale_p,
    int* __restrict__ gcur,
    int* __restrict__ etok, float* __restrict__ ew, int* __restrict__ slotof,
    int nent)
{
    const int e = blockIdx.x * BLOCK + threadIdx.x;
    if (e >= nent) return;
    const int p = tki[e];
    const int slot = atomicAdd(&gcur[p], 1);
    etok[slot] = e >> 2;
    ew[slot]   = tkw[e] * scale_p[0];
    slotof[e]  = slot;
}

// ---------------------------------------------------------------------------
// K2 (R16): down-projection, TWO consecutive tiles per block (same chunk c).
// Consecutive tiles usually share a pattern (contiguous tile ranges), so the
// 16 KB vd panel is staged once and reused. Chunk c stays in the low 3 bits
// of blockIdx -> chunk->XCD L2 affinity preserved. Inner body verbatim R11.
__global__ __launch_bounds__(BLOCK, 6) void proj_kernel(
    const float* __restrict__ x,
    const float* __restrict__ vd,          // [NPAT, DDIM, PDIM]
    const int* __restrict__ offs,
    const int* __restrict__ etok,
    const int* __restrict__ tile2p,
    const int* __restrict__ tilei,
    float* __restrict__ part,              // [NCHP][nent+1][PDIM]
    int maxt, int nent)
{
    __shared__ float vd_s[DCHP * PDIM];    // 16 KB
    __shared__ float x_s[GT * DCHP];       // 8 KB
    __shared__ int   gt[GT];
    __shared__ int   gs[GT];

    const int pr = blockIdx.x >> 3;
    const int c  = blockIdx.x & 7;
    const int t0 = pr * 2;
    if (t0 >= maxt || tile2p[t0] < 0) return;

    const int tid  = threadIdx.x;
    const int lane = tid & 63;
    const int wv   = tid >> 6;
    const int pp4  = lane & 7;
    const int seg  = lane >> 3;
    float* partc = part + (size_t)c * (size_t)(nent + 1) * PDIM;

    int lastp = -1;
    for (int ti = 0; ti < 2; ++ti) {
        const int tb = t0 + ti;
        if (tb >= maxt) break;
        const int p = tile2p[tb];
        if (p < 0) break;
        const int off0 = offs[p] + tilei[tb] * GT;
        const int gv   = min(GT, offs[p + 1] - off0);

        __syncthreads();                   // prior tile's vd_s/x_s/gt reads done
        if (p != lastp) {
            const float* vdp = vd + (size_t)p * DDIM * PDIM + (size_t)c * DCHP * PDIM;
            #pragma unroll
            for (int k = 0; k < 4; ++k)
                ((float4*)vd_s)[k * 256 + tid] = ((const float4*)vdp)[k * 256 + tid];
            lastp = p;
        }
        if (tid < GT) {
            if (tid < gv) { gt[tid] = etok[off0 + tid]; gs[tid] = off0 + tid; }
            else          { gt[tid] = etok[off0];       gs[tid] = nent; }
        }
        __syncthreads();

        #pragma unroll
        for (int k = 0; k < 2; ++k) {
            const int q  = k * 256 + tid;
            const int g  = q >> 5, fi = q & 31;
            ((float4*)x_s)[g * 32 + fi] =
                *(const float4*)(x + (size_t)gt[g] * DDIM + c * DCHP + fi * 4);
        }
        __syncthreads();

        float4 acc[4];
        #pragma unroll
        for (int j = 0; j < 4; ++j) acc[j] = make_float4(0.f, 0.f, 0.f, 0.f);

        #pragma unroll
        for (int i4 = 0; i4 < 4; ++i4) {
            const int d0 = seg * 16 + i4 * 4;
            const float4 v0 = *(const float4*)&vd_s[(d0 + 0) * PDIM + pp4 * 4];
            const float4 v1 = *(const float4*)&vd_s[(d0 + 1) * PDIM + pp4 * 4];
            const float4 v2 = *(const float4*)&vd_s[(d0 + 2) * PDIM + pp4 * 4];
            const float4 v3 = *(const float4*)&vd_s[(d0 + 3) * PDIM + pp4 * 4];
            #pragma unroll
            for (int j = 0; j < 4; ++j) {
                const float4 xg = *(const float4*)&x_s[(wv * 4 + j) * DCHP + d0];
                acc[j].x = fmaf(xg.x, v0.x, acc[j].x);
                acc[j].y = fmaf(xg.x, v0.y, acc[j].y);
                acc[j].z = fmaf(xg.x, v0.z, acc[j].z);
                acc[j].w = fmaf(xg.x, v0.w, acc[j].w);
                acc[j].x = fmaf(xg.y, v1.x, acc[j].x);
                acc[j].y = fmaf(xg.y, v1.y, acc[j].y);
                acc[j].z = fmaf(xg.y, v1.z, acc[j].z);
                acc[j].w = fmaf(xg.y, v1.w, acc[j].w);
                acc[j].x = fmaf(xg.z, v2.x, acc[j].x);
                acc[j].y = fmaf(xg.z, v2.y, acc[j].y);
                acc[j].z = fmaf(xg.z, v2.z, acc[j].z);
                acc[j].w = fmaf(xg.z, v2.w, acc[j].w);
                acc[j].x = fmaf(xg.w, v3.x, acc[j].x);
                acc[j].y = fmaf(xg.w, v3.y, acc[j].y);
                acc[j].z = fmaf(xg.w, v3.z, acc[j].z);
                acc[j].w = fmaf(xg.w, v3.w, acc[j].w);
            }
        }

        #pragma unroll
        for (int j = 0; j < 4; ++j) {
            #pragma unroll
            for (int off = 8; off <= 32; off <<= 1) {
                acc[j].x += __shfl_xor(acc[j].x, off, 64);
                acc[j].y += __shfl_xor(acc[j].y, off, 64);
                acc[j].z += __shfl_xor(acc[j].z, off, 64);
                acc[j].w += __shfl_xor(acc[j].w, off, 64);
            }
        }

        if ((lane & 0x38) == 0) {
            #pragma unroll
            for (int j = 0; j < 4; ++j)
                *(float4*)&partc[(size_t)gs[wv * 4 + j] * PDIM + pp4 * 4] = acc[j];
        }
    }
}

// ---------------------------------------------------------------------------
// K2b (R15, validated): projW[r] = silu(sum_c part[c][r]) * ew[r].
__global__ __launch_bounds__(BLOCK) void silu_kernel(
    const float* __restrict__ part,        // [NCHP][nent+1][PDIM]
    const float* __restrict__ ew,          // [nent]
    float* __restrict__ projW,             // [nent+1][PDIM]
    int nent)
{
    const int idx = blockIdx.x * BLOCK + threadIdx.x;
    const int total = (nent + 1) * PDIM;
    if (idx >= total) return;
    const int r = idx >> 5;
    const size_t PS = (size_t)(nent + 1) * PDIM;
    float s = 0.f;
    #pragma unroll
    for (int c = 0; c < NCHP; ++c) s += part[(size_t)c * PS + idx];
    const float w = (r < nent) ? ew[r] : 0.f;
    projW[idx] = (s / (1.f + expf(-s))) * w;
}

// ---------------------------------------------------------------------------
// K3 (R15, validated): up-projection, projW prologue; grid maxt*8.
template <int MODE>
__global__ __launch_bounds__(BLOCK, 6) void up_kernel(
    const float* __restrict__ vu,          // [NPAT, PDIM, DDIM]
    const int* __restrict__ offs,
    const int* __restrict__ etok,
    const int* __restrict__ tile2p,
    const int* __restrict__ tilei,
    const float* __restrict__ projW,       // [nent+1][PDIM]
    float* __restrict__ dst,               // contrib (MODE 0) or out (MODE 1)
    int nent)
{
    __shared__ float vu_s[PDIM * DCHP];    // 16 KB
    __shared__ float projT[PDIM][20];
    __shared__ int   gt[GT];
    __shared__ int   gs[GT];

    const int tb  = blockIdx.x >> 3;
    const int c   = blockIdx.x & 7;
    const int p   = tile2p[tb];
    if (p < 0) return;
    const int tid = threadIdx.x;
    const int off0 = offs[p] + tilei[tb] * GT;
    const int gv   = min(GT, offs[p + 1] - off0);

    const float* vup = vu + (size_t)p * PDIM * DDIM + (size_t)c * DCHP;
    #pragma unroll
    for (int k = 0; k < 4; ++k) {
        const int q  = k * 256 + tid;
        const int pp = q >> 5, fi = q & 31;
        *(float4*)&vu_s[pp * DCHP + fi * 4] =
            *(const float4*)(vup + (size_t)pp * DDIM + fi * 4);
    }
    if (tid < GT) {
        if (tid < gv) { gt[tid] = etok[off0 + tid]; gs[tid] = off0 + tid; }
        else          { gt[tid] = etok[off0];       gs[tid] = nent; }
    }
    __syncthreads();

    #pragma unroll
    for (int r = 0; r < 2; ++r) {
        const int idx = tid + r * BLOCK;
        const int g = idx >> 5, pp = idx & 31;
        projT[pp][g] = projW[(size_t)gs[g] * PDIM + pp];
    }
    __syncthreads();

    const int tg  = tid >> 5;
    const int l32 = tid & 31;
    const int g0 = tg * 2, g1 = tg * 2 + 1;

    float4 o0 = make_float4(0.f, 0.f, 0.f, 0.f);
    float4 o1 = o0;
    #pragma unroll
    for (int pp = 0; pp < PDIM; ++pp) {
        const float4 vu4 = *(const float4*)&vu_s[pp * DCHP + l32 * 4];
        const float a = projT[pp][g0];
        const float b = projT[pp][g1];
        o0.x = fmaf(a, vu4.x, o0.x); o0.y = fmaf(a, vu4.y, o0.y);
        o0.z = fmaf(a, vu4.z, o0.z); o0.w = fmaf(a, vu4.w, o0.w);
        o1.x = fmaf(b, vu4.x, o1.x); o1.y = fmaf(b, vu4.y, o1.y);
        o1.z = fmaf(b, vu4.z, o1.z); o1.w = fmaf(b, vu4.w, o1.w);
    }

    if (MODE == 0) {
        *(float4*)(dst + (size_t)gs[g0] * DDIM + c * DCHP + l32 * 4) = o0;
        *(float4*)(dst + (size_t)gs[g1] * DDIM + c * DCHP + l32 * 4) = o1;
    } else {
        if (g0 < gv) {
            float* op = dst + (size_t)gt[g0] * DDIM + c * DCHP + l32 * 4;
            atomicAdd(op + 0, o0.x); atomicAdd(op + 1, o0.y);
            atomicAdd(op + 2, o0.z); atomicAdd(op + 3, o0.w);
        }
        if (g1 < gv) {
            float* op = dst + (size_t)gt[g1] * DDIM + c * DCHP + l32 * 4;
            atomicAdd(op + 0, o1.x); atomicAdd(op + 1, o1.y);
            atomicAdd(op + 2, o1.z); atomicAdd(op + 3, o1.w);
        }
    }
}

// ---------------------------------------------------------------------------
// K4: out[t] = x[t] + sum_k contrib[slotof[t][k]]  (verbatim-verified)
__global__ __launch_bounds__(BLOCK) void combine_kernel(
    const float* __restrict__ x, const float* __restrict__ contrib,
    const int* __restrict__ slotof, float* __restrict__ out)
{
    __shared__ int sl[TOPK];
    const int t = blockIdx.x, tid = threadIdx.x;
    if (tid < TOPK) sl[tid] = slotof[t * TOPK + tid];
    __syncthreads();
    float4 r = ((const float4*)(x + (size_t)t * DDIM))[tid];
    #pragma unroll
    for (int k = 0; k < TOPK; ++k) {
        const float4 cv = ((const float4*)(contrib + (size_t)sl[k] * DDIM))[tid];
        r.x += cv.x; r.y += cv.y; r.z += cv.z; r.w += cv.w;
    }
    ((float4*)(out + (size_t)t * DDIM))[tid] = r;
}

// ---------------------------------------------------------------------------
extern "C" void kernel_launch(void* const* d_in, const int* in_sizes, int n_in,
                              void* d_out, int out_size, void* d_ws, size_t ws_size,
                              hipStream_t stream) {
    const float* x        = (const float*)d_in[0];
    const float* hasher_w = (const float*)d_in[1];
    const float* keys     = (const float*)d_in[2];
    const float* vd       = (const float*)d_in[3];
    const float* vu       = (const float*)d_in[4];
    const float* scale    = (const float*)d_in[5];
    float* out = (float*)d_out;

    const int ntok = in_sizes[0] / DDIM;        // B*T
    if (ntok <= 0) return;
    const int nent = ntok * TOPK;
    const int maxt = (nent + GT - 1) / GT + NPAT;   // worst-case tile count

    // workspace layout
    char* w = (char*)d_ws;
    const size_t o_gcnt = 0;                                      // 256 int
    const size_t o_gcur = 1024;                                   // 256 int
    const size_t o_offs = 2048;                                   // 257 int
    const size_t o_tki  = 4096;                                   // nent int
    const size_t o_tkw  = o_tki  + (size_t)nent * 4;
    const size_t o_etok = o_tkw  + (size_t)nent * 4;
    const size_t o_ew   = o_etok + (size_t)nent * 4;
    const size_t o_slot = o_ew   + (size_t)nent * 4;
    const size_t o_t2p  = o_slot + (size_t)nent * 4;
    const size_t o_tli  = o_t2p  + (size_t)maxt * 4;
    const size_t o_part = (o_tli + (size_t)maxt * 4 + 255) & ~(size_t)255;
    const size_t partsz = (size_t)NCHP * (size_t)(nent + 1) * PDIM * 4;
    const size_t o_pw   = (o_part + partsz + 255) & ~(size_t)255;
    const size_t pwsz   = (size_t)(nent + 1) * PDIM * 4;
    const size_t o_ctb  = (o_pw + pwsz + 255) & ~(size_t)255;
    const size_t needPW      = o_ctb;                              // atomic path
    const size_t needContrib = o_ctb + (size_t)(nent + 1) * DDIM * 4;

    int*   gcount = (int*)(w + o_gcnt);
    int*   gcur   = (int*)(w + o_gcur);
    int*   offs   = (int*)(w + o_offs);
    int*   tki    = (int*)(w + o_tki);
    float* tkw    = (float*)(w + o_tkw);
    int*   etok   = (int*)(w + o_etok);
    float* ew     = (float*)(w + o_ew);
    int*   slotof = (int*)(w + o_slot);
    int*   tile2p = (int*)(w + o_t2p);
    int*   tilei  = (int*)(w + o_tli);
    float* part   = (float*)(w + o_part);
    float* projW  = (float*)(w + o_pw);
    float* contrib= (float*)(w + o_ctb);

    hipMemsetAsync(gcount, 0, NPAT * sizeof(int), stream);

    const int rblocks = (ntok + RTPB - 1) / RTPB;
    hipLaunchKernelGGL(route_kernel, dim3(rblocks), dim3(BLOCK), 0, stream,
                       x, hasher_w, keys, tki, tkw, gcount, ntok);
    hipLaunchKernelGGL(scan_kernel, dim3(1), dim3(NPAT), 0, stream,
                       gcount, offs, gcur, tile2p, tilei, maxt);
    hipLaunchKernelGGL(fill_kernel, dim3((nent + BLOCK - 1) / BLOCK), dim3(BLOCK),
                       0, stream, tki, tkw, scale, gcur, etok, ew, slotof, nent);
    const int pairs = (maxt + 1) / 2;
    hipLaunchKernelGGL(proj_kernel, dim3(pairs * 8), dim3(BLOCK), 0, stream,
                       x, vd, offs, etok, tile2p, tilei, part, maxt, nent);
    hipLaunchKernelGGL(silu_kernel,
                       dim3(((nent + 1) * PDIM + BLOCK - 1) / BLOCK), dim3(BLOCK),
                       0, stream, part, ew, projW, nent);

    if (ws_size >= needContrib) {
        hipLaunchKernelGGL((up_kernel<0>), dim3(maxt * 8), dim3(BLOCK), 0, stream,
                           vu, offs, etok, tile2p, tilei, projW, contrib, nent);
        hipLaunchKernelGGL(combine_kernel, dim3(ntok), dim3(BLOCK), 0, stream,
                           x, contrib, slotof, out);
    } else if (ws_size >= needPW) {
        hipMemcpyAsync(out, x, (size_t)ntok * DDIM * 4, hipMemcpyDeviceToDevice,
                       stream);
        hipLaunchKernelGGL((up_kernel<1>), dim3(maxt * 8), dim3(BLOCK), 0, stream,
                           vu, offs, etok, tile2p, tilei, projW, out, nent);
    }
}

// Round 11
// 189.579 us; speedup vs baseline: 1.0897x; 1.0897x over previous
//
#include <hip/hip_runtime.h>
#include <math.h>
#include <float.h>

#define DDIM 1024   // D
#define PDIM 32     // pattern_dim
#define NPAT 256    // n_patterns
#define TOPK 4
#define BLOCK 256
#define GT   16     // tokens per tile
#define DCHP 128    // d-chunk
#define NCHP 8      // d-chunks (DDIM/DCHP)
#define RTPB 2      // tokens per route block (TWO waves per token)

// ---------------------------------------------------------------------------
// K0 (R17): routing with 2 WAVES per token (wave = (token, d-half)).
// Fixes the R10-diagnosed wave-starvation: 1 wave/token capped route at
// 2 waves/SIMD; splitting each token across 2 waves doubles TLP to 4/SIMD
// and halves per-wave LDS reads. hasher staged in LDS per 256-d segment
// (R12-validated); each wave FMAs only its 2 segments. The two halves merge
// in the padded transpose buffer (half0 writes, half1 accumulates).
// Reduce/sim/top4 duplicated across the wave pair (identical values);
// gcount atomic + output gated to half 0.
__global__ __launch_bounds__(BLOCK) void route_kernel(
    const float* __restrict__ x,
    const float* __restrict__ hasher_w,   // [PDIM, DDIM]
    const float* __restrict__ keys,       // [NPAT, PDIM]
    int*   __restrict__ tki,              // [ntok, TOPK]
    float* __restrict__ tkw,              // [ntok, TOPK]
    int*   __restrict__ gcount,           // [NPAT], pre-zeroed
    int ntok)
{
    // staging [32][256] = 8192 floats (32 KB); P regions 2*2112 = 4224 floats
    __shared__ float shmem[8192];
    __shared__ float h_s[RTPB][32];

    const int tid  = threadIdx.x;
    const int wv   = tid >> 6;            // 0..3
    const int lane = tid & 63;
    const int tl   = wv >> 1;             // local token 0..1
    const int half = wv & 1;              // d-half: segs {2h, 2h+1}
    const int traw = blockIdx.x * RTPB + tl;
    const int tok  = min(traw, ntok - 1);

    // ---- x: only my half's 2 segments (8 floats/lane)
    const float4* xrow = (const float4*)(x + (size_t)tok * DDIM);
    float4 xr[2];
    #pragma unroll
    for (int i = 0; i < 2; ++i) xr[i] = xrow[(half * 2 + i) * 64 + lane];

    float part[PDIM];
    #pragma unroll
    for (int pp = 0; pp < PDIM; ++pp) part[pp] = 0.f;

    float* hs = shmem;                    // [32][256] per segment
    for (int i = 0; i < 4; ++i) {
        #pragma unroll
        for (int k = 0; k < 8; ++k) {
            const int q  = k * 256 + tid;
            const int pp = q >> 6, fi = q & 63;
            ((float4*)hs)[q] =
                *(const float4*)(hasher_w + (size_t)pp * DDIM + i * 256 + fi * 4);
        }
        __syncthreads();
        if ((i >> 1) == half) {           // wave-uniform: my half only
            const int ii = i & 1;
            #pragma unroll
            for (int pp = 0; pp < PDIM; ++pp) {
                const float4 w4 = *(const float4*)&hs[pp * 256 + lane * 4];
                part[pp] = fmaf(xr[ii].x, w4.x, part[pp]);
                part[pp] = fmaf(xr[ii].y, w4.y, part[pp]);
                part[pp] = fmaf(xr[ii].z, w4.z, part[pp]);
                part[pp] = fmaf(xr[ii].w, w4.w, part[pp]);
            }
        }
        __syncthreads();
    }

    // ---- transpose-merge: half0 writes P, half1 accumulates (pad 33)
    float* P = shmem + tl * (64 * 33);
    if (half == 0) {
        #pragma unroll
        for (int pp = 0; pp < PDIM; ++pp) P[lane * 33 + pp] = part[pp];
    }
    __syncthreads();
    if (half == 1) {
        #pragma unroll
        for (int pp = 0; pp < PDIM; ++pp) P[lane * 33 + pp] += part[pp];
    }
    __syncthreads();

    // ---- reduce (duplicated across the token's 2 waves; identical values)
    {
        const int pp = lane & 31, h32 = lane >> 5;
        float hsum = 0.f;
        #pragma unroll 8
        for (int i = 0; i < 32; ++i)
            hsum += P[(h32 * 32 + i) * 33 + pp];
        hsum += __shfl_xor(hsum, 32, 64);
        if (h32 == 0) h_s[tl][pp] = hsum;
    }
    __syncthreads();

    // ---- sim + top4 + softmax (verbatim logic, validated)
    float4 h4[8];
    #pragma unroll
    for (int i = 0; i < 8; ++i) h4[i] = *(const float4*)&h_s[tl][i * 4];

    float sc0, sc1, sc2, sc3;
    {
        float sv[4];
        #pragma unroll
        for (int c = 0; c < 4; ++c) {
            const float4* kr = (const float4*)(keys + (size_t)(c * 64 + lane) * PDIM);
            float a = 0.f;
            #pragma unroll
            for (int i = 0; i < 8; ++i) {
                const float4 k4 = kr[i];
                a = fmaf(k4.x, h4[i].x, a); a = fmaf(k4.y, h4[i].y, a);
                a = fmaf(k4.z, h4[i].z, a); a = fmaf(k4.w, h4[i].w, a);
            }
            sv[c] = a;
        }
        sc0 = sv[0]; sc1 = sv[1]; sc2 = sv[2]; sc3 = sv[3];
    }

    float wval[TOPK]; int widx[TOPK];
    #pragma unroll
    for (int r = 0; r < TOPK; ++r) {
        float bv = sc0; int bc = 0;
        if (sc1 > bv) { bv = sc1; bc = 1; }
        if (sc2 > bv) { bv = sc2; bc = 2; }
        if (sc3 > bv) { bv = sc3; bc = 3; }
        int bidx = bc * 64 + lane;
        #pragma unroll
        for (int off = 1; off < 64; off <<= 1) {
            const float ov = __shfl_xor(bv, off, 64);
            const int   oi = __shfl_xor(bidx, off, 64);
            if (ov > bv || (ov == bv && oi < bidx)) { bv = ov; bidx = oi; }
        }
        wval[r] = bv; widx[r] = bidx;
        if ((bidx & 63) == lane) {
            const int c = bidx >> 6;
            if (c == 0) sc0 = -FLT_MAX;
            else if (c == 1) sc1 = -FLT_MAX;
            else if (c == 2) sc2 = -FLT_MAX;
            else sc3 = -FLT_MAX;
        }
    }

    if (lane == 0 && half == 0 && traw < ntok) {
        float m = wval[0];
        #pragma unroll
        for (int k = 1; k < TOPK; ++k) m = fmaxf(m, wval[k]);
        float s = 0.f, e[TOPK];
        #pragma unroll
        for (int k = 0; k < TOPK; ++k) { e[k] = expf(wval[k] - m); s += e[k]; }
        #pragma unroll
        for (int k = 0; k < TOPK; ++k) {
            tki[tok * TOPK + k] = widx[k];
            tkw[tok * TOPK + k] = e[k] / s;
            atomicAdd(&gcount[widx[k]], 1);
        }
    }
}

// ---------------------------------------------------------------------------
// K1a (R12, validated): scan gcount -> offs, init gcur, tile list.
__global__ __launch_bounds__(NPAT) void scan_kernel(
    const int* __restrict__ gcount,
    int* __restrict__ offs,
    int* __restrict__ gcur,
    int* __restrict__ tile2p, int* __restrict__ tilei,
    int maxt)
{
    __shared__ int s[NPAT];
    const int tid = threadIdx.x;

    const int v = gcount[tid];
    s[tid] = v;
    __syncthreads();
    for (int off = 1; off < NPAT; off <<= 1) {
        int t = 0;
        if (tid >= off) t = s[tid - off];
        __syncthreads();
        s[tid] += t;
        __syncthreads();
    }
    const int incl = s[tid];
    offs[tid + 1] = incl;
    if (tid == 0) offs[0] = 0;
    gcur[tid] = incl - v;

    const int tc = (v + GT - 1) / GT;
    __syncthreads();
    s[tid] = tc;
    __syncthreads();
    for (int off = 1; off < NPAT; off <<= 1) {
        int t = 0;
        if (tid >= off) t = s[tid - off];
        __syncthreads();
        s[tid] += t;
        __syncthreads();
    }
    const int toff = s[tid] - tc;
    for (int i = tid; i < maxt; i += NPAT) tile2p[i] = -1;
    __syncthreads();
    for (int i = 0; i < tc; ++i) { tile2p[toff + i] = tid; tilei[toff + i] = i; }
}

// ---------------------------------------------------------------------------
// K1b (R12, validated): parallel CSR fill.
__global__ __launch_bounds__(BLOCK) void fill_kernel(
    const int* __restrict__ tki, const float* __restrict__ tkw,
    const float* __restrict__ scale_p,
    int* __restrict__ gcur,
    int* __restrict__ etok, float* __restrict__ ew, int* __restrict__ slotof,
    int nent)
{
    const int e = blockIdx.x * BLOCK + threadIdx.x;
    if (e >= nent) return;
    const int p = tki[e];
    const int slot = atomicAdd(&gcur[p], 1);
    etok[slot] = e >> 2;
    ew[slot]   = tkw[e] * scale_p[0];
    slotof[e]  = slot;
}

// ---------------------------------------------------------------------------
// K2 (R11/R9, validated at 183 us): down-projection, one (tile, 128-d chunk)
// per block. Grid tb*8+c preserves chunk->XCD L2 affinity.
__global__ __launch_bounds__(BLOCK, 6) void proj_kernel(
    const float* __restrict__ x,
    const float* __restrict__ vd,          // [NPAT, DDIM, PDIM]
    const int* __restrict__ offs,
    const int* __restrict__ etok,
    const int* __restrict__ tile2p,
    const int* __restrict__ tilei,
    float* __restrict__ part,              // [NCHP][nent+1][PDIM]
    int nent)
{
    __shared__ float vd_s[DCHP * PDIM];    // 16 KB
    __shared__ float x_s[GT * DCHP];       // 8 KB
    __shared__ int   gt[GT];
    __shared__ int   gs[GT];

    const int tb  = blockIdx.x >> 3;
    const int c   = blockIdx.x & 7;
    const int p   = tile2p[tb];
    if (p < 0) return;
    const int tid = threadIdx.x;
    const int off0 = offs[p] + tilei[tb] * GT;
    const int gv   = min(GT, offs[p + 1] - off0);

    const float* vdp = vd + (size_t)p * DDIM * PDIM + (size_t)c * DCHP * PDIM;
    #pragma unroll
    for (int k = 0; k < 4; ++k)
        ((float4*)vd_s)[k * 256 + tid] = ((const float4*)vdp)[k * 256 + tid];

    if (tid < GT) {
        if (tid < gv) { gt[tid] = etok[off0 + tid]; gs[tid] = off0 + tid; }
        else          { gt[tid] = etok[off0];       gs[tid] = nent; }
    }
    __syncthreads();

    #pragma unroll
    for (int k = 0; k < 2; ++k) {
        const int q  = k * 256 + tid;
        const int g  = q >> 5, fi = q & 31;
        ((float4*)x_s)[g * 32 + fi] =
            *(const float4*)(x + (size_t)gt[g] * DDIM + c * DCHP + fi * 4);
    }
    __syncthreads();

    const int lane = tid & 63;
    const int wv   = tid >> 6;
    const int pp4  = lane & 7;
    const int seg  = lane >> 3;

    float4 acc[4];
    #pragma unroll
    for (int j = 0; j < 4; ++j) acc[j] = make_float4(0.f, 0.f, 0.f, 0.f);

    #pragma unroll
    for (int i4 = 0; i4 < 4; ++i4) {
        const int d0 = seg * 16 + i4 * 4;
        const float4 v0 = *(const float4*)&vd_s[(d0 + 0) * PDIM + pp4 * 4];
        const float4 v1 = *(const float4*)&vd_s[(d0 + 1) * PDIM + pp4 * 4];
        const float4 v2 = *(const float4*)&vd_s[(d0 + 2) * PDIM + pp4 * 4];
        const float4 v3 = *(const float4*)&vd_s[(d0 + 3) * PDIM + pp4 * 4];
        #pragma unroll
        for (int j = 0; j < 4; ++j) {
            const float4 xg = *(const float4*)&x_s[(wv * 4 + j) * DCHP + d0];
            acc[j].x = fmaf(xg.x, v0.x, acc[j].x);
            acc[j].y = fmaf(xg.x, v0.y, acc[j].y);
            acc[j].z = fmaf(xg.x, v0.z, acc[j].z);
            acc[j].w = fmaf(xg.x, v0.w, acc[j].w);
            acc[j].x = fmaf(xg.y, v1.x, acc[j].x);
            acc[j].y = fmaf(xg.y, v1.y, acc[j].y);
            acc[j].z = fmaf(xg.y, v1.z, acc[j].z);
            acc[j].w = fmaf(xg.y, v1.w, acc[j].w);
            acc[j].x = fmaf(xg.z, v2.x, acc[j].x);
            acc[j].y = fmaf(xg.z, v2.y, acc[j].y);
            acc[j].z = fmaf(xg.z, v2.z, acc[j].z);
            acc[j].w = fmaf(xg.z, v2.w, acc[j].w);
            acc[j].x = fmaf(xg.w, v3.x, acc[j].x);
            acc[j].y = fmaf(xg.w, v3.y, acc[j].y);
            acc[j].z = fmaf(xg.w, v3.z, acc[j].z);
            acc[j].w = fmaf(xg.w, v3.w, acc[j].w);
        }
    }

    #pragma unroll
    for (int j = 0; j < 4; ++j) {
        #pragma unroll
        for (int off = 8; off <= 32; off <<= 1) {
            acc[j].x += __shfl_xor(acc[j].x, off, 64);
            acc[j].y += __shfl_xor(acc[j].y, off, 64);
            acc[j].z += __shfl_xor(acc[j].z, off, 64);
            acc[j].w += __shfl_xor(acc[j].w, off, 64);
        }
    }

    float* partc = part + (size_t)c * (size_t)(nent + 1) * PDIM;
    if ((lane & 0x38) == 0) {
        #pragma unroll
        for (int j = 0; j < 4; ++j)
            *(float4*)&partc[(size_t)gs[wv * 4 + j] * PDIM + pp4 * 4] = acc[j];
    }
}

// ---------------------------------------------------------------------------
// K2b (R15, validated): projW[r] = silu(sum_c part[c][r]) * ew[r].
__global__ __launch_bounds__(BLOCK) void silu_kernel(
    const float* __restrict__ part,        // [NCHP][nent+1][PDIM]
    const float* __restrict__ ew,          // [nent]
    float* __restrict__ projW,             // [nent+1][PDIM]
    int nent)
{
    const int idx = blockIdx.x * BLOCK + threadIdx.x;
    const int total = (nent + 1) * PDIM;
    if (idx >= total) return;
    const int r = idx >> 5;
    const size_t PS = (size_t)(nent + 1) * PDIM;
    float s = 0.f;
    #pragma unroll
    for (int c = 0; c < NCHP; ++c) s += part[(size_t)c * PS + idx];
    const float w = (r < nent) ? ew[r] : 0.f;
    projW[idx] = (s / (1.f + expf(-s))) * w;
}

// ---------------------------------------------------------------------------
// K3 (R15, validated): up-projection, projW prologue; grid maxt*8.
template <int MODE>
__global__ __launch_bounds__(BLOCK, 6) void up_kernel(
    const float* __restrict__ vu,          // [NPAT, PDIM, DDIM]
    const int* __restrict__ offs,
    const int* __restrict__ etok,
    const int* __restrict__ tile2p,
    const int* __restrict__ tilei,
    const float* __restrict__ projW,       // [nent+1][PDIM]
    float* __restrict__ dst,               // contrib (MODE 0) or out (MODE 1)
    int nent)
{
    __shared__ float vu_s[PDIM * DCHP];    // 16 KB
    __shared__ float projT[PDIM][20];
    __shared__ int   gt[GT];
    __shared__ int   gs[GT];

    const int tb  = blockIdx.x >> 3;
    const int c   = blockIdx.x & 7;
    const int p   = tile2p[tb];
    if (p < 0) return;
    const int tid = threadIdx.x;
    const int off0 = offs[p] + tilei[tb] * GT;
    const int gv   = min(GT, offs[p + 1] - off0);

    const float* vup = vu + (size_t)p * PDIM * DDIM + (size_t)c * DCHP;
    #pragma unroll
    for (int k = 0; k < 4; ++k) {
        const int q  = k * 256 + tid;
        const int pp = q >> 5, fi = q & 31;
        *(float4*)&vu_s[pp * DCHP + fi * 4] =
            *(const float4*)(vup + (size_t)pp * DDIM + fi * 4);
    }
    if (tid < GT) {
        if (tid < gv) { gt[tid] = etok[off0 + tid]; gs[tid] = off0 + tid; }
        else          { gt[tid] = etok[off0];       gs[tid] = nent; }
    }
    __syncthreads();

    #pragma unroll
    for (int r = 0; r < 2; ++r) {
        const int idx = tid + r * BLOCK;
        const int g = idx >> 5, pp = idx & 31;
        projT[pp][g] = projW[(size_t)gs[g] * PDIM + pp];
    }
    __syncthreads();

    const int tg  = tid >> 5;
    const int l32 = tid & 31;
    const int g0 = tg * 2, g1 = tg * 2 + 1;

    float4 o0 = make_float4(0.f, 0.f, 0.f, 0.f);
    float4 o1 = o0;
    #pragma unroll
    for (int pp = 0; pp < PDIM; ++pp) {
        const float4 vu4 = *(const float4*)&vu_s[pp * DCHP + l32 * 4];
        const float a = projT[pp][g0];
        const float b = projT[pp][g1];
        o0.x = fmaf(a, vu4.x, o0.x); o0.y = fmaf(a, vu4.y, o0.y);
        o0.z = fmaf(a, vu4.z, o0.z); o0.w = fmaf(a, vu4.w, o0.w);
        o1.x = fmaf(b, vu4.x, o1.x); o1.y = fmaf(b, vu4.y, o1.y);
        o1.z = fmaf(b, vu4.z, o1.z); o1.w = fmaf(b, vu4.w, o1.w);
    }

    if (MODE == 0) {
        *(float4*)(dst + (size_t)gs[g0] * DDIM + c * DCHP + l32 * 4) = o0;
        *(float4*)(dst + (size_t)gs[g1] * DDIM + c * DCHP + l32 * 4) = o1;
    } else {
        if (g0 < gv) {
            float* op = dst + (size_t)gt[g0] * DDIM + c * DCHP + l32 * 4;
            atomicAdd(op + 0, o0.x); atomicAdd(op + 1, o0.y);
            atomicAdd(op + 2, o0.z); atomicAdd(op + 3, o0.w);
        }
        if (g1 < gv) {
            float* op = dst + (size_t)gt[g1] * DDIM + c * DCHP + l32 * 4;
            atomicAdd(op + 0, o1.x); atomicAdd(op + 1, o1.y);
            atomicAdd(op + 2, o1.z); atomicAdd(op + 3, o1.w);
        }
    }
}

// ---------------------------------------------------------------------------
// K4: out[t] = x[t] + sum_k contrib[slotof[t][k]]  (verbatim-verified)
__global__ __launch_bounds__(BLOCK) void combine_kernel(
    const float* __restrict__ x, const float* __restrict__ contrib,
    const int* __restrict__ slotof, float* __restrict__ out)
{
    __shared__ int sl[TOPK];
    const int t = blockIdx.x, tid = threadIdx.x;
    if (tid < TOPK) sl[tid] = slotof[t * TOPK + tid];
    __syncthreads();
    float4 r = ((const float4*)(x + (size_t)t * DDIM))[tid];
    #pragma unroll
    for (int k = 0; k < TOPK; ++k) {
        const float4 cv = ((const float4*)(contrib + (size_t)sl[k] * DDIM))[tid];
        r.x += cv.x; r.y += cv.y; r.z += cv.z; r.w += cv.w;
    }
    ((float4*)(out + (size_t)t * DDIM))[tid] = r;
}

// ---------------------------------------------------------------------------
extern "C" void kernel_launch(void* const* d_in, const int* in_sizes, int n_in,
                              void* d_out, int out_size, void* d_ws, size_t ws_size,
                              hipStream_t stream) {
    const float* x        = (const float*)d_in[0];
    const float* hasher_w = (const float*)d_in[1];
    const float* keys     = (const float*)d_in[2];
    const float* vd       = (const float*)d_in[3];
    const float* vu       = (const float*)d_in[4];
    const float* scale    = (const float*)d_in[5];
    float* out = (float*)d_out;

    const int ntok = in_sizes[0] / DDIM;        // B*T
    if (ntok <= 0) return;
    const int nent = ntok * TOPK;
    const int maxt = (nent + GT - 1) / GT + NPAT;   // worst-case tile count

    // workspace layout
    char* w = (char*)d_ws;
    const size_t o_gcnt = 0;                                      // 256 int
    const size_t o_gcur = 1024;                                   // 256 int
    const size_t o_offs = 2048;                                   // 257 int
    const size_t o_tki  = 4096;                                   // nent int
    const size_t o_tkw  = o_tki  + (size_t)nent * 4;
    const size_t o_etok = o_tkw  + (size_t)nent * 4;
    const size_t o_ew   = o_etok + (size_t)nent * 4;
    const size_t o_slot = o_ew   + (size_t)nent * 4;
    const size_t o_t2p  = o_slot + (size_t)nent * 4;
    const size_t o_tli  = o_t2p  + (size_t)maxt * 4;
    const size_t o_part = (o_tli + (size_t)maxt * 4 + 255) & ~(size_t)255;
    const size_t partsz = (size_t)NCHP * (size_t)(nent + 1) * PDIM * 4;
    const size_t o_pw   = (o_part + partsz + 255) & ~(size_t)255;
    const size_t pwsz   = (size_t)(nent + 1) * PDIM * 4;
    const size_t o_ctb  = (o_pw + pwsz + 255) & ~(size_t)255;
    const size_t needPW      = o_ctb;                              // atomic path
    const size_t needContrib = o_ctb + (size_t)(nent + 1) * DDIM * 4;

    int*   gcount = (int*)(w + o_gcnt);
    int*   gcur   = (int*)(w + o_gcur);
    int*   offs   = (int*)(w + o_offs);
    int*   tki    = (int*)(w + o_tki);
    float* tkw    = (float*)(w + o_tkw);
    int*   etok   = (int*)(w + o_etok);
    float* ew     = (float*)(w + o_ew);
    int*   slotof = (int*)(w + o_slot);
    int*   tile2p = (int*)(w + o_t2p);
    int*   tilei  = (int*)(w + o_tli);
    float* part   = (float*)(w + o_part);
    float* projW  = (float*)(w + o_pw);
    float* contrib= (float*)(w + o_ctb);

    hipMemsetAsync(gcount, 0, NPAT * sizeof(int), stream);

    const int rblocks = (ntok + RTPB - 1) / RTPB;
    hipLaunchKernelGGL(route_kernel, dim3(rblocks), dim3(BLOCK), 0, stream,
                       x, hasher_w, keys, tki, tkw, gcount, ntok);
    hipLaunchKernelGGL(scan_kernel, dim3(1), dim3(NPAT), 0, stream,
                       gcount, offs, gcur, tile2p, tilei, maxt);
    hipLaunchKernelGGL(fill_kernel, dim3((nent + BLOCK - 1) / BLOCK), dim3(BLOCK),
                       0, stream, tki, tkw, scale, gcur, etok, ew, slotof, nent);
    hipLaunchKernelGGL(proj_kernel, dim3(maxt * 8), dim3(BLOCK), 0, stream,
                       x, vd, offs, etok, tile2p, tilei, part, nent);
    hipLaunchKernelGGL(silu_kernel,
                       dim3(((nent + 1) * PDIM + BLOCK - 1) / BLOCK), dim3(BLOCK),
                       0, stream, part, ew, projW, nent);

    if (ws_size >= needContrib) {
        hipLaunchKernelGGL((up_kernel<0>), dim3(maxt * 8), dim3(BLOCK), 0, stream,
                           vu, offs, etok, tile2p, tilei, projW, contrib, nent);
        hipLaunchKernelGGL(combine_kernel, dim3(ntok), dim3(BLOCK), 0, stream,
                           x, contrib, slotof, out);
    } else if (ws_size >= needPW) {
        hipMemcpyAsync(out, x, (size_t)ntok * DDIM * 4, hipMemcpyDeviceToDevice,
                       stream);
        hipLaunchKernelGGL((up_kernel<1>), dim3(maxt * 8), dim3(BLOCK), 0, stream,
                           vu, offs, etok, tile2p, tilei, projW, out, nent);
    }
}

// Round 12
// 183.624 us; speedup vs baseline: 1.1250x; 1.0324x over previous
//
#include <hip/hip_runtime.h>
#include <math.h>
#include <float.h>

#define DDIM 1024   // D
#define PDIM 32     // pattern_dim
#define NPAT 256    // n_patterns
#define TOPK 4
#define BLOCK 256
#define GT   16     // tokens per tile
#define DCHP 128    // d-chunk
#define NCHP 8      // d-chunks (DDIM/DCHP)
#define RTPB 4      // tokens per route block (one per wave)

// ---------------------------------------------------------------------------
// K0 (R12, validated best at 183.0 us): routing, one WAVE per token,
// 4 tokens/block, 512 blocks. hasher_w staged in LDS per 256-d segment,
// lane-0 atomics into gcount. Three alternatives measured worse:
// de-staged (47us, latency-bound), 2 tok/wave (75us, VGPR), 2 waves/tok
// (+6.6us, staging x2 + dup top4). This shape is the local optimum.
__global__ __launch_bounds__(BLOCK) void route_kernel(
    const float* __restrict__ x,
    const float* __restrict__ hasher_w,   // [PDIM, DDIM]
    const float* __restrict__ keys,       // [NPAT, PDIM]
    int*   __restrict__ tki,              // [ntok, TOPK]
    float* __restrict__ tkw,              // [ntok, TOPK]
    int*   __restrict__ gcount,           // [NPAT], pre-zeroed
    int ntok)
{
    __shared__ float shmem[RTPB * 64 * 33];   // 33.8 KB dual-purpose
    __shared__ float h_s[RTPB][32];

    const int tid  = threadIdx.x;
    const int wv   = tid >> 6;
    const int lane = tid & 63;
    const int traw = blockIdx.x * RTPB + wv;
    const int tok  = min(traw, ntok - 1);

    const float4* xrow = (const float4*)(x + (size_t)tok * DDIM);
    float4 xr[4];
    #pragma unroll
    for (int i = 0; i < 4; ++i) xr[i] = xrow[i * 64 + lane];

    float part[PDIM];
    #pragma unroll
    for (int pp = 0; pp < PDIM; ++pp) part[pp] = 0.f;

    float* hs = shmem;
    for (int i = 0; i < 4; ++i) {
        #pragma unroll
        for (int k = 0; k < 8; ++k) {
            const int q  = k * 256 + tid;
            const int pp = q >> 6, fi = q & 63;
            ((float4*)hs)[q] =
                *(const float4*)(hasher_w + (size_t)pp * DDIM + i * 256 + fi * 4);
        }
        __syncthreads();
        #pragma unroll
        for (int pp = 0; pp < PDIM; ++pp) {
            const float4 w4 = *(const float4*)&hs[pp * 256 + lane * 4];
            part[pp] = fmaf(xr[i].x, w4.x, part[pp]);
            part[pp] = fmaf(xr[i].y, w4.y, part[pp]);
            part[pp] = fmaf(xr[i].z, w4.z, part[pp]);
            part[pp] = fmaf(xr[i].w, w4.w, part[pp]);
        }
        __syncthreads();
    }

    float* P = shmem + wv * (64 * 33);
    #pragma unroll
    for (int pp = 0; pp < PDIM; ++pp) P[lane * 33 + pp] = part[pp];
    __syncthreads();

    {
        const int pp = lane & 31, half = lane >> 5;
        float hsum = 0.f;
        #pragma unroll 8
        for (int i = 0; i < 32; ++i)
            hsum += P[(half * 32 + i) * 33 + pp];
        hsum += __shfl_xor(hsum, 32, 64);
        if (half == 0) h_s[wv][pp] = hsum;
    }
    __syncthreads();

    float4 h4[8];
    #pragma unroll
    for (int i = 0; i < 8; ++i) h4[i] = *(const float4*)&h_s[wv][i * 4];

    float sc0, sc1, sc2, sc3;
    {
        float sv[4];
        #pragma unroll
        for (int c = 0; c < 4; ++c) {
            const float4* kr = (const float4*)(keys + (size_t)(c * 64 + lane) * PDIM);
            float a = 0.f;
            #pragma unroll
            for (int i = 0; i < 8; ++i) {
                const float4 k4 = kr[i];
                a = fmaf(k4.x, h4[i].x, a); a = fmaf(k4.y, h4[i].y, a);
                a = fmaf(k4.z, h4[i].z, a); a = fmaf(k4.w, h4[i].w, a);
            }
            sv[c] = a;
        }
        sc0 = sv[0]; sc1 = sv[1]; sc2 = sv[2]; sc3 = sv[3];
    }

    float wval[TOPK]; int widx[TOPK];
    #pragma unroll
    for (int r = 0; r < TOPK; ++r) {
        float bv = sc0; int bc = 0;
        if (sc1 > bv) { bv = sc1; bc = 1; }
        if (sc2 > bv) { bv = sc2; bc = 2; }
        if (sc3 > bv) { bv = sc3; bc = 3; }
        int bidx = bc * 64 + lane;
        #pragma unroll
        for (int off = 1; off < 64; off <<= 1) {
            const float ov = __shfl_xor(bv, off, 64);
            const int   oi = __shfl_xor(bidx, off, 64);
            if (ov > bv || (ov == bv && oi < bidx)) { bv = ov; bidx = oi; }
        }
        wval[r] = bv; widx[r] = bidx;
        if ((bidx & 63) == lane) {
            const int c = bidx >> 6;
            if (c == 0) sc0 = -FLT_MAX;
            else if (c == 1) sc1 = -FLT_MAX;
            else if (c == 2) sc2 = -FLT_MAX;
            else sc3 = -FLT_MAX;
        }
    }

    if (lane == 0 && traw < ntok) {
        float m = wval[0];
        #pragma unroll
        for (int k = 1; k < TOPK; ++k) m = fmaxf(m, wval[k]);
        float s = 0.f, e[TOPK];
        #pragma unroll
        for (int k = 0; k < TOPK; ++k) { e[k] = expf(wval[k] - m); s += e[k]; }
        #pragma unroll
        for (int k = 0; k < TOPK; ++k) {
            tki[tok * TOPK + k] = widx[k];
            tkw[tok * TOPK + k] = e[k] / s;
            atomicAdd(&gcount[widx[k]], 1);
        }
    }
}

// ---------------------------------------------------------------------------
// K1a (R12, validated): scan gcount -> offs, init gcur, tile list.
__global__ __launch_bounds__(NPAT) void scan_kernel(
    const int* __restrict__ gcount,
    int* __restrict__ offs,
    int* __restrict__ gcur,
    int* __restrict__ tile2p, int* __restrict__ tilei,
    int maxt)
{
    __shared__ int s[NPAT];
    const int tid = threadIdx.x;

    const int v = gcount[tid];
    s[tid] = v;
    __syncthreads();
    for (int off = 1; off < NPAT; off <<= 1) {
        int t = 0;
        if (tid >= off) t = s[tid - off];
        __syncthreads();
        s[tid] += t;
        __syncthreads();
    }
    const int incl = s[tid];
    offs[tid + 1] = incl;
    if (tid == 0) offs[0] = 0;
    gcur[tid] = incl - v;

    const int tc = (v + GT - 1) / GT;
    __syncthreads();
    s[tid] = tc;
    __syncthreads();
    for (int off = 1; off < NPAT; off <<= 1) {
        int t = 0;
        if (tid >= off) t = s[tid - off];
        __syncthreads();
        s[tid] += t;
        __syncthreads();
    }
    const int toff = s[tid] - tc;
    for (int i = tid; i < maxt; i += NPAT) tile2p[i] = -1;
    __syncthreads();
    for (int i = 0; i < tc; ++i) { tile2p[toff + i] = tid; tilei[toff + i] = i; }
}

// ---------------------------------------------------------------------------
// K1b (R12, validated): parallel CSR fill.
__global__ __launch_bounds__(BLOCK) void fill_kernel(
    const int* __restrict__ tki, const float* __restrict__ tkw,
    const float* __restrict__ scale_p,
    int* __restrict__ gcur,
    int* __restrict__ etok, float* __restrict__ ew, int* __restrict__ slotof,
    int nent)
{
    const int e = blockIdx.x * BLOCK + threadIdx.x;
    if (e >= nent) return;
    const int p = tki[e];
    const int slot = atomicAdd(&gcur[p], 1);
    etok[slot] = e >> 2;
    ew[slot]   = tkw[e] * scale_p[0];
    slotof[e]  = slot;
}

// ---------------------------------------------------------------------------
// K2 (R11/R9, validated at 183 us): down-projection, one (tile, 128-d chunk)
// per block. Grid tb*8+c preserves chunk->XCD L2 affinity.
__global__ __launch_bounds__(BLOCK, 6) void proj_kernel(
    const float* __restrict__ x,
    const float* __restrict__ vd,          // [NPAT, DDIM, PDIM]
    const int* __restrict__ offs,
    const int* __restrict__ etok,
    const int* __restrict__ tile2p,
    const int* __restrict__ tilei,
    float* __restrict__ part,              // [NCHP][nent+1][PDIM]
    int nent)
{
    __shared__ float vd_s[DCHP * PDIM];    // 16 KB
    __shared__ float x_s[GT * DCHP];       // 8 KB
    __shared__ int   gt[GT];
    __shared__ int   gs[GT];

    const int tb  = blockIdx.x >> 3;
    const int c   = blockIdx.x & 7;
    const int p   = tile2p[tb];
    if (p < 0) return;
    const int tid = threadIdx.x;
    const int off0 = offs[p] + tilei[tb] * GT;
    const int gv   = min(GT, offs[p + 1] - off0);

    const float* vdp = vd + (size_t)p * DDIM * PDIM + (size_t)c * DCHP * PDIM;
    #pragma unroll
    for (int k = 0; k < 4; ++k)
        ((float4*)vd_s)[k * 256 + tid] = ((const float4*)vdp)[k * 256 + tid];

    if (tid < GT) {
        if (tid < gv) { gt[tid] = etok[off0 + tid]; gs[tid] = off0 + tid; }
        else          { gt[tid] = etok[off0];       gs[tid] = nent; }
    }
    __syncthreads();

    #pragma unroll
    for (int k = 0; k < 2; ++k) {
        const int q  = k * 256 + tid;
        const int g  = q >> 5, fi = q & 31;
        ((float4*)x_s)[g * 32 + fi] =
            *(const float4*)(x + (size_t)gt[g] * DDIM + c * DCHP + fi * 4);
    }
    __syncthreads();

    const int lane = tid & 63;
    const int wv   = tid >> 6;
    const int pp4  = lane & 7;
    const int seg  = lane >> 3;

    float4 acc[4];
    #pragma unroll
    for (int j = 0; j < 4; ++j) acc[j] = make_float4(0.f, 0.f, 0.f, 0.f);

    #pragma unroll
    for (int i4 = 0; i4 < 4; ++i4) {
        const int d0 = seg * 16 + i4 * 4;
        const float4 v0 = *(const float4*)&vd_s[(d0 + 0) * PDIM + pp4 * 4];
        const float4 v1 = *(const float4*)&vd_s[(d0 + 1) * PDIM + pp4 * 4];
        const float4 v2 = *(const float4*)&vd_s[(d0 + 2) * PDIM + pp4 * 4];
        const float4 v3 = *(const float4*)&vd_s[(d0 + 3) * PDIM + pp4 * 4];
        #pragma unroll
        for (int j = 0; j < 4; ++j) {
            const float4 xg = *(const float4*)&x_s[(wv * 4 + j) * DCHP + d0];
            acc[j].x = fmaf(xg.x, v0.x, acc[j].x);
            acc[j].y = fmaf(xg.x, v0.y, acc[j].y);
            acc[j].z = fmaf(xg.x, v0.z, acc[j].z);
            acc[j].w = fmaf(xg.x, v0.w, acc[j].w);
            acc[j].x = fmaf(xg.y, v1.x, acc[j].x);
            acc[j].y = fmaf(xg.y, v1.y, acc[j].y);
            acc[j].z = fmaf(xg.y, v1.z, acc[j].z);
            acc[j].w = fmaf(xg.y, v1.w, acc[j].w);
            acc[j].x = fmaf(xg.z, v2.x, acc[j].x);
            acc[j].y = fmaf(xg.z, v2.y, acc[j].y);
            acc[j].z = fmaf(xg.z, v2.z, acc[j].z);
            acc[j].w = fmaf(xg.z, v2.w, acc[j].w);
            acc[j].x = fmaf(xg.w, v3.x, acc[j].x);
            acc[j].y = fmaf(xg.w, v3.y, acc[j].y);
            acc[j].z = fmaf(xg.w, v3.z, acc[j].z);
            acc[j].w = fmaf(xg.w, v3.w, acc[j].w);
        }
    }

    #pragma unroll
    for (int j = 0; j < 4; ++j) {
        #pragma unroll
        for (int off = 8; off <= 32; off <<= 1) {
            acc[j].x += __shfl_xor(acc[j].x, off, 64);
            acc[j].y += __shfl_xor(acc[j].y, off, 64);
            acc[j].z += __shfl_xor(acc[j].z, off, 64);
            acc[j].w += __shfl_xor(acc[j].w, off, 64);
        }
    }

    float* partc = part + (size_t)c * (size_t)(nent + 1) * PDIM;
    if ((lane & 0x38) == 0) {
        #pragma unroll
        for (int j = 0; j < 4; ++j)
            *(float4*)&partc[(size_t)gs[wv * 4 + j] * PDIM + pp4 * 4] = acc[j];
    }
}

// ---------------------------------------------------------------------------
// K2b (R15, validated): projW[r] = silu(sum_c part[c][r]) * ew[r].
__global__ __launch_bounds__(BLOCK) void silu_kernel(
    const float* __restrict__ part,        // [NCHP][nent+1][PDIM]
    const float* __restrict__ ew,          // [nent]
    float* __restrict__ projW,             // [nent+1][PDIM]
    int nent)
{
    const int idx = blockIdx.x * BLOCK + threadIdx.x;
    const int total = (nent + 1) * PDIM;
    if (idx >= total) return;
    const int r = idx >> 5;
    const size_t PS = (size_t)(nent + 1) * PDIM;
    float s = 0.f;
    #pragma unroll
    for (int c = 0; c < NCHP; ++c) s += part[(size_t)c * PS + idx];
    const float w = (r < nent) ? ew[r] : 0.f;
    projW[idx] = (s / (1.f + expf(-s))) * w;
}

// ---------------------------------------------------------------------------
// K3 (R15, validated): up-projection, projW prologue; grid maxt*8.
template <int MODE>
__global__ __launch_bounds__(BLOCK, 6) void up_kernel(
    const float* __restrict__ vu,          // [NPAT, PDIM, DDIM]
    const int* __restrict__ offs,
    const int* __restrict__ etok,
    const int* __restrict__ tile2p,
    const int* __restrict__ tilei,
    const float* __restrict__ projW,       // [nent+1][PDIM]
    float* __restrict__ dst,               // contrib (MODE 0) or out (MODE 1)
    int nent)
{
    __shared__ float vu_s[PDIM * DCHP];    // 16 KB
    __shared__ float projT[PDIM][20];
    __shared__ int   gt[GT];
    __shared__ int   gs[GT];

    const int tb  = blockIdx.x >> 3;
    const int c   = blockIdx.x & 7;
    const int p   = tile2p[tb];
    if (p < 0) return;
    const int tid = threadIdx.x;
    const int off0 = offs[p] + tilei[tb] * GT;
    const int gv   = min(GT, offs[p + 1] - off0);

    const float* vup = vu + (size_t)p * PDIM * DDIM + (size_t)c * DCHP;
    #pragma unroll
    for (int k = 0; k < 4; ++k) {
        const int q  = k * 256 + tid;
        const int pp = q >> 5, fi = q & 31;
        *(float4*)&vu_s[pp * DCHP + fi * 4] =
            *(const float4*)(vup + (size_t)pp * DDIM + fi * 4);
    }
    if (tid < GT) {
        if (tid < gv) { gt[tid] = etok[off0 + tid]; gs[tid] = off0 + tid; }
        else          { gt[tid] = etok[off0];       gs[tid] = nent; }
    }
    __syncthreads();

    #pragma unroll
    for (int r = 0; r < 2; ++r) {
        const int idx = tid + r * BLOCK;
        const int g = idx >> 5, pp = idx & 31;
        projT[pp][g] = projW[(size_t)gs[g] * PDIM + pp];
    }
    __syncthreads();

    const int tg  = tid >> 5;
    const int l32 = tid & 31;
    const int g0 = tg * 2, g1 = tg * 2 + 1;

    float4 o0 = make_float4(0.f, 0.f, 0.f, 0.f);
    float4 o1 = o0;
    #pragma unroll
    for (int pp = 0; pp < PDIM; ++pp) {
        const float4 vu4 = *(const float4*)&vu_s[pp * DCHP + l32 * 4];
        const float a = projT[pp][g0];
        const float b = projT[pp][g1];
        o0.x = fmaf(a, vu4.x, o0.x); o0.y = fmaf(a, vu4.y, o0.y);
        o0.z = fmaf(a, vu4.z, o0.z); o0.w = fmaf(a, vu4.w, o0.w);
        o1.x = fmaf(b, vu4.x, o1.x); o1.y = fmaf(b, vu4.y, o1.y);
        o1.z = fmaf(b, vu4.z, o1.z); o1.w = fmaf(b, vu4.w, o1.w);
    }

    if (MODE == 0) {
        *(float4*)(dst + (size_t)gs[g0] * DDIM + c * DCHP + l32 * 4) = o0;
        *(float4*)(dst + (size_t)gs[g1] * DDIM + c * DCHP + l32 * 4) = o1;
    } else {
        if (g0 < gv) {
            float* op = dst + (size_t)gt[g0] * DDIM + c * DCHP + l32 * 4;
            atomicAdd(op + 0, o0.x); atomicAdd(op + 1, o0.y);
            atomicAdd(op + 2, o0.z); atomicAdd(op + 3, o0.w);
        }
        if (g1 < gv) {
            float* op = dst + (size_t)gt[g1] * DDIM + c * DCHP + l32 * 4;
            atomicAdd(op + 0, o1.x); atomicAdd(op + 1, o1.y);
            atomicAdd(op + 2, o1.z); atomicAdd(op + 3, o1.w);
        }
    }
}

// ---------------------------------------------------------------------------
// K4: out[t] = x[t] + sum_k contrib[slotof[t][k]]  (verbatim-verified)
__global__ __launch_bounds__(BLOCK) void combine_kernel(
    const float* __restrict__ x, const float* __restrict__ contrib,
    const int* __restrict__ slotof, float* __restrict__ out)
{
    __shared__ int sl[TOPK];
    const int t = blockIdx.x, tid = threadIdx.x;
    if (tid < TOPK) sl[tid] = slotof[t * TOPK + tid];
    __syncthreads();
    float4 r = ((const float4*)(x + (size_t)t * DDIM))[tid];
    #pragma unroll
    for (int k = 0; k < TOPK; ++k) {
        const float4 cv = ((const float4*)(contrib + (size_t)sl[k] * DDIM))[tid];
        r.x += cv.x; r.y += cv.y; r.z += cv.z; r.w += cv.w;
    }
    ((float4*)(out + (size_t)t * DDIM))[tid] = r;
}

// ---------------------------------------------------------------------------
extern "C" void kernel_launch(void* const* d_in, const int* in_sizes, int n_in,
                              void* d_out, int out_size, void* d_ws, size_t ws_size,
                              hipStream_t stream) {
    const float* x        = (const float*)d_in[0];
    const float* hasher_w = (const float*)d_in[1];
    const float* keys     = (const float*)d_in[2];
    const float* vd       = (const float*)d_in[3];
    const float* vu       = (const float*)d_in[4];
    const float* scale    = (const float*)d_in[5];
    float* out = (float*)d_out;

    const int ntok = in_sizes[0] / DDIM;        // B*T
    if (ntok <= 0) return;
    const int nent = ntok * TOPK;
    const int maxt = (nent + GT - 1) / GT + NPAT;   // worst-case tile count

    // workspace layout
    char* w = (char*)d_ws;
    const size_t o_gcnt = 0;                                      // 256 int
    const size_t o_gcur = 1024;                                   // 256 int
    const size_t o_offs = 2048;                                   // 257 int
    const size_t o_tki  = 4096;                                   // nent int
    const size_t o_tkw  = o_tki  + (size_t)nent * 4;
    const size_t o_etok = o_tkw  + (size_t)nent * 4;
    const size_t o_ew   = o_etok + (size_t)nent * 4;
    const size_t o_slot = o_ew   + (size_t)nent * 4;
    const size_t o_t2p  = o_slot + (size_t)nent * 4;
    const size_t o_tli  = o_t2p  + (size_t)maxt * 4;
    const size_t o_part = (o_tli + (size_t)maxt * 4 + 255) & ~(size_t)255;
    const size_t partsz = (size_t)NCHP * (size_t)(nent + 1) * PDIM * 4;
    const size_t o_pw   = (o_part + partsz + 255) & ~(size_t)255;
    const size_t pwsz   = (size_t)(nent + 1) * PDIM * 4;
    const size_t o_ctb  = (o_pw + pwsz + 255) & ~(size_t)255;
    const size_t needPW      = o_ctb;                              // atomic path
    const size_t needContrib = o_ctb + (size_t)(nent + 1) * DDIM * 4;

    int*   gcount = (int*)(w + o_gcnt);
    int*   gcur   = (int*)(w + o_gcur);
    int*   offs   = (int*)(w + o_offs);
    int*   tki    = (int*)(w + o_tki);
    float* tkw    = (float*)(w + o_tkw);
    int*   etok   = (int*)(w + o_etok);
    float* ew     = (float*)(w + o_ew);
    int*   slotof = (int*)(w + o_slot);
    int*   tile2p = (int*)(w + o_t2p);
    int*   tilei  = (int*)(w + o_tli);
    float* part   = (float*)(w + o_part);
    float* projW  = (float*)(w + o_pw);
    float* contrib= (float*)(w + o_ctb);

    hipMemsetAsync(gcount, 0, NPAT * sizeof(int), stream);

    const int rblocks = (ntok + RTPB - 1) / RTPB;
    hipLaunchKernelGGL(route_kernel, dim3(rblocks), dim3(BLOCK), 0, stream,
                       x, hasher_w, keys, tki, tkw, gcount, ntok);
    hipLaunchKernelGGL(scan_kernel, dim3(1), dim3(NPAT), 0, stream,
                       gcount, offs, gcur, tile2p, tilei, maxt);
    hipLaunchKernelGGL(fill_kernel, dim3((nent + BLOCK - 1) / BLOCK), dim3(BLOCK),
                       0, stream, tki, tkw, scale, gcur, etok, ew, slotof, nent);
    hipLaunchKernelGGL(proj_kernel, dim3(maxt * 8), dim3(BLOCK), 0, stream,
                       x, vd, offs, etok, tile2p, tilei, part, nent);
    hipLaunchKernelGGL(silu_kernel,
                       dim3(((nent + 1) * PDIM + BLOCK - 1) / BLOCK), dim3(BLOCK),
                       0, stream, part, ew, projW, nent);

    if (ws_size >= needContrib) {
        hipLaunchKernelGGL((up_kernel<0>), dim3(maxt * 8), dim3(BLOCK), 0, stream,
                           vu, offs, etok, tile2p, tilei, projW, contrib, nent);
        hipLaunchKernelGGL(combine_kernel, dim3(ntok), dim3(BLOCK), 0, stream,
                           x, contrib, slotof, out);
    } else if (ws_size >= needPW) {
        hipMemcpyAsync(out, x, (size_t)ntok * DDIM * 4, hipMemcpyDeviceToDevice,
                       stream);
        hipLaunchKernelGGL((up_kernel<1>), dim3(maxt * 8), dim3(BLOCK), 0, stream,
                           vu, offs, etok, tile2p, tilei, projW, out, nent);
    }
}